// Round 14
// baseline (453.177 us; speedup 1.0000x reference)
//
#include <hip/hip_runtime.h>
#include <hip/hip_bf16.h>
#include <stdint.h>

#define B_   256
#define C_   10
#define S_   500
#define H_   256
#define OUT_ 500
#define M_   (B_ * S_)   // 128000
#define FCK  (S_ * H_)   // 128000
#define ND   16          // Chebyshev nodes (degree 15)
#define KE   24000       // extended K: [hi|hi|lo] x 500*16
#define PI_F 3.14159265358979f

typedef __attribute__((ext_vector_type(8))) short s16x8;   // 8 bf16
typedef __attribute__((ext_vector_type(4))) float f32x4;

__device__ __forceinline__ unsigned short f2bf(float f) {
  union { float f; unsigned u; } v; v.f = f;
  unsigned r = v.u + 0x7fffu + ((v.u >> 16) & 1u);   // RNE
  return (unsigned short)(r >> 16);
}
__device__ __forceinline__ float bf2f(unsigned short u) {
  union { unsigned u; float f; } v; v.u = ((unsigned)u) << 16; return v.f;
}
__device__ __forceinline__ float sigf(float x) { return 1.0f / (1.0f + __expf(-x)); }
__device__ __forceinline__ float tanh_f(float x) { return 1.0f - 2.0f / (__expf(2.0f * x) + 1.0f); }

// pack 8 f32 -> 8 bf16 via v_cvt_pk_bf16_f32 (S0 low 16, S1 high 16; RNE)
__device__ __forceinline__ s16x8 pack_bf16x8(f32x4 a, f32x4 b) {
  union { s16x8 v; unsigned u[4]; } r;
  asm("v_cvt_pk_bf16_f32 %0, %1, %2" : "=v"(r.u[0]) : "v"(a[0]), "v"(a[1]));
  asm("v_cvt_pk_bf16_f32 %0, %1, %2" : "=v"(r.u[1]) : "v"(a[2]), "v"(a[3]));
  asm("v_cvt_pk_bf16_f32 %0, %1, %2" : "=v"(r.u[2]) : "v"(b[0]), "v"(b[1]));
  asm("v_cvt_pk_bf16_f32 %0, %1, %2" : "=v"(r.u[3]) : "v"(b[2]), "v"(b[3]));
  return r.v;
}

// split 8 f32 into bf16 hi + bf16 lo (lo = x - f32(hi))
__device__ __forceinline__ void split8(f32x4 a, f32x4 b, s16x8* hi, s16x8* lo) {
  union { s16x8 v; unsigned u[4]; } h;
  h.v = pack_bf16x8(a, b);
  union { unsigned u; float f; } c;
  f32x4 ra, rb;
  c.u = h.u[0] << 16;          ra[0] = c.f;
  c.u = h.u[0] & 0xffff0000u;  ra[1] = c.f;
  c.u = h.u[1] << 16;          ra[2] = c.f;
  c.u = h.u[1] & 0xffff0000u;  ra[3] = c.f;
  c.u = h.u[2] << 16;          rb[0] = c.f;
  c.u = h.u[2] & 0xffff0000u;  rb[1] = c.f;
  c.u = h.u[3] << 16;          rb[2] = c.f;
  c.u = h.u[3] & 0xffff0000u;  rb[3] = c.f;
  *hi = h.v;
  *lo = pack_bf16x8(a - ra, b - rb);
}

// ---- conv center tap + relu: y[b*S+s] ----
__global__ void k_conv(const float* __restrict__ x, const float* __restrict__ cw,
                       const float* __restrict__ cb, float* __restrict__ y) {
  int n = blockIdx.x * 256 + threadIdx.x;            // 128000 exact
  int b = n / S_, s = n - b * S_;
  const float* xp = x + (size_t)b * C_ * S_ + s;
  float acc = cb[0];
#pragma unroll
  for (int c = 0; c < C_; ++c) acc += xp[c * S_] * cw[c * 5 + 2];
  y[n] = fmaxf(acc, 0.0f);
}

// ---- h0 at the 16 Chebyshev nodes (pure f32) ----
__global__ void k_h0n(const float* __restrict__ w0, const float* __restrict__ bi0,
                      const float* __restrict__ bh0, float* __restrict__ h0n) {
  int tid = blockIdx.x * 256 + threadIdx.x;          // 4096
  int j = tid >> 8, k = tid & 255;
  float th = PI_F * ((float)j + 0.5f) / 16.0f;
  float yv = (cosf(th) + 1.0f) * 0.5f;               // node in [0,1]
  float gi = yv * w0[k] + bi0[k] + bh0[k];
  float gg = yv * w0[512 + k] + bi0[512 + k] + bh0[512 + k];
  float go = yv * w0[768 + k] + bi0[768 + k] + bh0[768 + k];
  float c = sigf(gi) * tanh_f(gg);
  h0n[tid] = sigf(go) * tanh_f(c);
}

// ---- h1 at the nodes (f32 dots against original f32 w_ih1) ----
__global__ void k_h1n(const float* __restrict__ h0n, const float* __restrict__ w1,
                      const float* __restrict__ b1i, const float* __restrict__ b1h,
                      float* __restrict__ h1n) {
  int tid = blockIdx.x * 256 + threadIdx.x;          // 4096
  int j = tid >> 8, col = tid & 255;
  const float* h  = h0n + j * 256;
  const float* wi = w1 + (size_t)col * 256;
  const float* wg = w1 + (size_t)(512 + col) * 256;
  const float* wo = w1 + (size_t)(768 + col) * 256;
  float gi = b1i[col] + b1h[col];
  float gg = b1i[512 + col] + b1h[512 + col];
  float go = b1i[768 + col] + b1h[768 + col];
  for (int k = 0; k < 256; ++k) {
    float hv = h[k];
    gi += hv * wi[k]; gg += hv * wg[k]; go += hv * wo[k];
  }
  float c = sigf(gi) * tanh_f(gg);
  h1n[tid] = sigf(go) * tanh_f(c);
}

// ---- Chebyshev coefficients via DCT-II -> ctf[k][16] f32 (k-major) ----
__global__ void k_cheb(const float* __restrict__ h1n, float* __restrict__ ctf) {
  int tid = blockIdx.x * 256 + threadIdx.x;          // 4096
  int d = tid >> 8, k = tid & 255;
  float s = 0.f;
  for (int j = 0; j < 16; ++j)
    s += h1n[j * 256 + k] * cosf(PI_F * (float)d * ((float)j + 0.5f) / 16.0f);
  ctf[k * 16 + d] = s * ((d == 0) ? (1.0f / 16.0f) : (2.0f / 16.0f));
}

// ---- P-gen: A'[b][s*16+d] = [T_hi | T_hi | T_lo], T_d = Cheb(2*min(y,1)-1) ----
__global__ void k_pgen(const float* __restrict__ y, unsigned short* __restrict__ Ps) {
  int n = blockIdx.x * 256 + threadIdx.x;            // 128000 exact
  float xv = 2.0f * fminf(y[n], 1.0f) - 1.0f;
  float T[16];
  T[0] = 1.0f; T[1] = xv;
#pragma unroll
  for (int d = 2; d < 16; ++d) T[d] = 2.0f * xv * T[d - 1] - T[d - 2];
  f32x4 t0 = {T[0], T[1], T[2], T[3]},   t1 = {T[4], T[5], T[6], T[7]};
  f32x4 t2 = {T[8], T[9], T[10], T[11]}, t3 = {T[12], T[13], T[14], T[15]};
  s16x8 h0v, l0v, h1v, l1v;
  split8(t0, t1, &h0v, &l0v);
  split8(t2, t3, &h1v, &l1v);
  int bb = n / S_, ss = n - bb * S_;
  unsigned short* base = Ps + (size_t)bb * KE + ss * 16;
  *(s16x8*)(base)         = h0v;  *(s16x8*)(base + 8)         = h1v;
  *(s16x8*)(base + 8000)  = h0v;  *(s16x8*)(base + 8008)      = h1v;
  *(s16x8*)(base + 16000) = l0v;  *(s16x8*)(base + 16008)     = l1v;
}

// ---- Q v4: streaming reduction, 2 threads/row (lane pairs), nontemporal
// loads, software-pipelined bursts, in-wave shfl_xor reduce. No LDS/MFMA.
__global__ __launch_bounds__(256) void k_q(
    const float* __restrict__ W, const float* __restrict__ ctf,
    unsigned short* __restrict__ Qs) {
  int tid = blockIdx.x * 256 + threadIdx.x;          // grid 1954 -> 500224
  int os = tid >> 1;
  if (os >= 250000) return;
  const int half = tid & 1;                          // lane l pairs with l^1
  const float* wp = W + (size_t)os * 256 + half * 128;
  f32x4 a0 = {0.f,0.f,0.f,0.f}, a1 = a0, a2 = a0, a3 = a0;

  f32x4 wva[8], wvb[8];
#pragma unroll
  for (int i = 0; i < 8; ++i)
    wva[i] = __builtin_nontemporal_load((const f32x4*)(wp + i * 4));

#define QCOMP(ARR, KB)                                                        \
  {                                                                           \
    _Pragma("unroll")                                                         \
    for (int i = 0; i < 8; ++i) {                                             \
      _Pragma("unroll")                                                       \
      for (int j = 0; j < 4; ++j) {                                           \
        const float* cp = ctf + ((KB) + i * 4 + j) * 16;                      \
        f32x4 c0 = *(const f32x4*)cp;                                         \
        f32x4 c1 = *(const f32x4*)(cp + 4);                                   \
        f32x4 c2 = *(const f32x4*)(cp + 8);                                   \
        f32x4 c3 = *(const f32x4*)(cp + 12);                                  \
        float wsc = ARR[i][j];                                                \
        a0 += wsc * c0; a1 += wsc * c1; a2 += wsc * c2; a3 += wsc * c3;       \
      }                                                                       \
    }                                                                         \
  }

  // prefetch next burst while computing current (static names, rule #20)
#pragma unroll
  for (int i = 0; i < 8; ++i)
    wvb[i] = __builtin_nontemporal_load((const f32x4*)(wp + 32 + i * 4));
  QCOMP(wva, half * 128 + 0);
#pragma unroll
  for (int i = 0; i < 8; ++i)
    wva[i] = __builtin_nontemporal_load((const f32x4*)(wp + 64 + i * 4));
  QCOMP(wvb, half * 128 + 32);
#pragma unroll
  for (int i = 0; i < 8; ++i)
    wvb[i] = __builtin_nontemporal_load((const f32x4*)(wp + 96 + i * 4));
  QCOMP(wva, half * 128 + 64);
  QCOMP(wvb, half * 128 + 96);
#undef QCOMP

  // pair-reduce: lane l + lane l^1 hold halves of the same row
#pragma unroll
  for (int e = 0; e < 4; ++e) {
    a0[e] += __shfl_xor(a0[e], 1);
    a1[e] += __shfl_xor(a1[e], 1);
    a2[e] += __shfl_xor(a2[e], 1);
    a3[e] += __shfl_xor(a3[e], 1);
  }
  if (half == 0) {
    int o = os / 500, s = os - o * 500;
    s16x8 hi01, lo01, hi23, lo23;
    split8(a0, a1, &hi01, &lo01);
    split8(a2, a3, &hi23, &lo23);
    unsigned short* qb = Qs + (size_t)o * KE + s * 16;
    *(s16x8*)(qb)          = hi01;  *(s16x8*)(qb + 8)     = hi23;
    *(s16x8*)(qb + 8000)   = lo01;  *(s16x8*)(qb + 8008)  = lo23;
    *(s16x8*)(qb + 16000)  = hi01;  *(s16x8*)(qb + 16008) = hi23;
  }
}

// ---- final GEMM: pfc[ks] += A'(256xKE) . B'(500xKE)^T over ks-chunk of 960 ----
// grid 400 = ks(25) x bm(2) x bo(8); 4 waves, no LDS, no barriers.
__global__ __launch_bounds__(256) void k_fc(
    const unsigned short* __restrict__ Ps, const unsigned short* __restrict__ Qs,
    float* __restrict__ pfc) {
  const int blk = blockIdx.x;
  const int ks = blk % 25, rest = blk / 25;
  const int bm = rest & 1, bo = rest >> 1;
  const int lane = threadIdx.x & 63, nw = threadIdx.x >> 6;
  const int kbase = ks * 960;
  const int ob = bo * 64 + nw * 16 + (lane & 15);
  const int obc = ob > 499 ? 499 : ob;
  const unsigned short* bp = Qs + (size_t)obc * KE + kbase + (lane >> 4) * 8;
  const unsigned short* ap = Ps + (size_t)(bm * 128 + (lane & 15)) * KE + kbase + (lane >> 4) * 8;
  f32x4 acc[8] = {};
#pragma unroll 3
  for (int st = 0; st < 30; ++st) {
    s16x8 bf = *(const s16x8*)(bp + st * 32);
#pragma unroll
    for (int mf = 0; mf < 8; ++mf) {
      s16x8 af = *(const s16x8*)(ap + (size_t)mf * 16 * KE + st * 32);
      acc[mf] = __builtin_amdgcn_mfma_f32_16x16x32_bf16(af, bf, acc[mf], 0, 0, 0);
    }
  }
  const int col = bo * 64 + nw * 16 + (lane & 15);
  if (col < OUT_) {
    float* pp = pfc + (size_t)ks * 128000;
#pragma unroll
    for (int mf = 0; mf < 8; ++mf) {
#pragma unroll
      for (int r = 0; r < 4; ++r) {
        int row = bm * 128 + mf * 16 + (lane >> 4) * 4 + r;
        pp[row * OUT_ + col] = acc[mf][r];
      }
    }
  }
}

// ---- reduce: out[i] = fc_b[i%500] + sum_ks pfc[ks][i] ----
__global__ void k_red2(const float* __restrict__ pfc, const float* __restrict__ fcb,
                       float* __restrict__ out) {
  int i = blockIdx.x * 256 + threadIdx.x;            // 128000 exact
  int o = i % OUT_;
  float s = fcb[o];
#pragma unroll 5
  for (int ks = 0; ks < 25; ++ks) s += pfc[(size_t)ks * 128000 + i];
  out[i] = s;
}

extern "C" void kernel_launch(void* const* d_in, const int* in_sizes, int n_in,
                              void* d_out, int out_size, void* d_ws, size_t ws_size,
                              hipStream_t stream) {
  const float* x      = (const float*)d_in[0];
  const float* conv_w = (const float*)d_in[1];
  const float* conv_b = (const float*)d_in[2];
  const float* w_ih0  = (const float*)d_in[3];
  const float* b_ih0  = (const float*)d_in[4];
  const float* b_hh0  = (const float*)d_in[5];
  const float* w_ih1  = (const float*)d_in[6];
  const float* b_ih1  = (const float*)d_in[7];
  const float* b_hh1  = (const float*)d_in[8];
  const float* fc_w   = (const float*)d_in[9];
  const float* fc_b   = (const float*)d_in[10];
  float* out = (float*)d_out;

  char* ws = (char*)d_ws;
  float* y            = (float*)ws;                        // 512,000 B
  float* h0n          = (float*)(ws + 524288);             // 16,384 B
  float* h1n          = (float*)(ws + 540672);             // 16,384 B
  float* ctf          = (float*)(ws + 557056);             // 16,384 B
  unsigned short* Ps  = (unsigned short*)(ws + 1048576);   // 12,288,000 B
  unsigned short* Qs  = (unsigned short*)(ws + 14680064);  // 24,000,000 B
  float* pfc          = (float*)(ws + 41943040);           // 12,800,000 B

  k_conv<<<500, 256, 0, stream>>>(x, conv_w, conv_b, y);
  k_h0n<<<16, 256, 0, stream>>>(w_ih0, b_ih0, b_hh0, h0n);
  k_h1n<<<16, 256, 0, stream>>>(h0n, w_ih1, b_ih1, b_hh1, h1n);
  k_cheb<<<16, 256, 0, stream>>>(h1n, ctf);
  k_pgen<<<500, 256, 0, stream>>>(y, Ps);
  k_q<<<1954, 256, 0, stream>>>(fc_w, ctf, Qs);
  k_fc<<<400, 256, 0, stream>>>(Ps, Qs, pfc);
  k_red2<<<500, 256, 0, stream>>>(pfc, fc_b, out);
}

// Round 15
// 393.255 us; speedup vs baseline: 1.1524x; 1.1524x over previous
//
#include <hip/hip_runtime.h>
#include <hip/hip_bf16.h>
#include <stdint.h>

#define B_   256
#define C_   10
#define S_   500
#define H_   256
#define OUT_ 500
#define M_   (B_ * S_)   // 128000
#define FCK  (S_ * H_)   // 128000
#define ND   16          // Chebyshev nodes (degree 15)
#define KE   24000       // extended K: [hi|hi|lo] x 500*16
#define PI_F 3.14159265358979f

typedef __attribute__((ext_vector_type(8))) short s16x8;   // 8 bf16
typedef __attribute__((ext_vector_type(4))) float f32x4;

__device__ __forceinline__ unsigned short f2bf(float f) {
  union { float f; unsigned u; } v; v.f = f;
  unsigned r = v.u + 0x7fffu + ((v.u >> 16) & 1u);   // RNE
  return (unsigned short)(r >> 16);
}
__device__ __forceinline__ float bf2f(unsigned short u) {
  union { unsigned u; float f; } v; v.u = ((unsigned)u) << 16; return v.f;
}
__device__ __forceinline__ float sigf(float x) { return 1.0f / (1.0f + __expf(-x)); }
__device__ __forceinline__ float tanh_f(float x) { return 1.0f - 2.0f / (__expf(2.0f * x) + 1.0f); }

// pack 8 f32 -> 8 bf16 via v_cvt_pk_bf16_f32 (S0 low 16, S1 high 16; RNE)
__device__ __forceinline__ s16x8 pack_bf16x8(f32x4 a, f32x4 b) {
  union { s16x8 v; unsigned u[4]; } r;
  asm("v_cvt_pk_bf16_f32 %0, %1, %2" : "=v"(r.u[0]) : "v"(a[0]), "v"(a[1]));
  asm("v_cvt_pk_bf16_f32 %0, %1, %2" : "=v"(r.u[1]) : "v"(a[2]), "v"(a[3]));
  asm("v_cvt_pk_bf16_f32 %0, %1, %2" : "=v"(r.u[2]) : "v"(b[0]), "v"(b[1]));
  asm("v_cvt_pk_bf16_f32 %0, %1, %2" : "=v"(r.u[3]) : "v"(b[2]), "v"(b[3]));
  return r.v;
}

// split 8 f32 into bf16 hi + bf16 lo (lo = x - f32(hi))
__device__ __forceinline__ void split8(f32x4 a, f32x4 b, s16x8* hi, s16x8* lo) {
  union { s16x8 v; unsigned u[4]; } h;
  h.v = pack_bf16x8(a, b);
  union { unsigned u; float f; } c;
  f32x4 ra, rb;
  c.u = h.u[0] << 16;          ra[0] = c.f;
  c.u = h.u[0] & 0xffff0000u;  ra[1] = c.f;
  c.u = h.u[1] << 16;          ra[2] = c.f;
  c.u = h.u[1] & 0xffff0000u;  ra[3] = c.f;
  c.u = h.u[2] << 16;          rb[0] = c.f;
  c.u = h.u[2] & 0xffff0000u;  rb[1] = c.f;
  c.u = h.u[3] << 16;          rb[2] = c.f;
  c.u = h.u[3] & 0xffff0000u;  rb[3] = c.f;
  *hi = h.v;
  *lo = pack_bf16x8(a - ra, b - rb);
}

// ---- conv center tap + relu: y[b*S+s] ----
__global__ void k_conv(const float* __restrict__ x, const float* __restrict__ cw,
                       const float* __restrict__ cb, float* __restrict__ y) {
  int n = blockIdx.x * 256 + threadIdx.x;            // 128000 exact
  int b = n / S_, s = n - b * S_;
  const float* xp = x + (size_t)b * C_ * S_ + s;
  float acc = cb[0];
#pragma unroll
  for (int c = 0; c < C_; ++c) acc += xp[c * S_] * cw[c * 5 + 2];
  y[n] = fmaxf(acc, 0.0f);
}

// ---- h0 at the 16 Chebyshev nodes (pure f32) ----
__global__ void k_h0n(const float* __restrict__ w0, const float* __restrict__ bi0,
                      const float* __restrict__ bh0, float* __restrict__ h0n) {
  int tid = blockIdx.x * 256 + threadIdx.x;          // 4096
  int j = tid >> 8, k = tid & 255;
  float th = PI_F * ((float)j + 0.5f) / 16.0f;
  float yv = (cosf(th) + 1.0f) * 0.5f;               // node in [0,1]
  float gi = yv * w0[k] + bi0[k] + bh0[k];
  float gg = yv * w0[512 + k] + bi0[512 + k] + bh0[512 + k];
  float go = yv * w0[768 + k] + bi0[768 + k] + bh0[768 + k];
  float c = sigf(gi) * tanh_f(gg);
  h0n[tid] = sigf(go) * tanh_f(c);
}

// ---- h1 at the nodes (f32 dots against original f32 w_ih1) ----
__global__ void k_h1n(const float* __restrict__ h0n, const float* __restrict__ w1,
                      const float* __restrict__ b1i, const float* __restrict__ b1h,
                      float* __restrict__ h1n) {
  int tid = blockIdx.x * 256 + threadIdx.x;          // 4096
  int j = tid >> 8, col = tid & 255;
  const float* h  = h0n + j * 256;
  const float* wi = w1 + (size_t)col * 256;
  const float* wg = w1 + (size_t)(512 + col) * 256;
  const float* wo = w1 + (size_t)(768 + col) * 256;
  float gi = b1i[col] + b1h[col];
  float gg = b1i[512 + col] + b1h[512 + col];
  float go = b1i[768 + col] + b1h[768 + col];
  for (int k = 0; k < 256; ++k) {
    float hv = h[k];
    gi += hv * wi[k]; gg += hv * wg[k]; go += hv * wo[k];
  }
  float c = sigf(gi) * tanh_f(gg);
  h1n[tid] = sigf(go) * tanh_f(c);
}

// ---- Chebyshev coefficients via DCT-II -> ctf[k][16] f32 (k-major) ----
__global__ void k_cheb(const float* __restrict__ h1n, float* __restrict__ ctf) {
  int tid = blockIdx.x * 256 + threadIdx.x;          // 4096
  int d = tid >> 8, k = tid & 255;
  float s = 0.f;
  for (int j = 0; j < 16; ++j)
    s += h1n[j * 256 + k] * cosf(PI_F * (float)d * ((float)j + 0.5f) / 16.0f);
  ctf[k * 16 + d] = s * ((d == 0) ? (1.0f / 16.0f) : (2.0f / 16.0f));
}

// ---- P-gen: A'[b][s*16+d] = [T_hi | T_hi | T_lo], T_d = Cheb(2*min(y,1)-1) ----
__global__ void k_pgen(const float* __restrict__ y, unsigned short* __restrict__ Ps) {
  int n = blockIdx.x * 256 + threadIdx.x;            // 128000 exact
  float xv = 2.0f * fminf(y[n], 1.0f) - 1.0f;
  float T[16];
  T[0] = 1.0f; T[1] = xv;
#pragma unroll
  for (int d = 2; d < 16; ++d) T[d] = 2.0f * xv * T[d - 1] - T[d - 2];
  f32x4 t0 = {T[0], T[1], T[2], T[3]},   t1 = {T[4], T[5], T[6], T[7]};
  f32x4 t2 = {T[8], T[9], T[10], T[11]}, t3 = {T[12], T[13], T[14], T[15]};
  s16x8 h0v, l0v, h1v, l1v;
  split8(t0, t1, &h0v, &l0v);
  split8(t2, t3, &h1v, &l1v);
  int bb = n / S_, ss = n - bb * S_;
  unsigned short* base = Ps + (size_t)bb * KE + ss * 16;
  *(s16x8*)(base)         = h0v;  *(s16x8*)(base + 8)         = h1v;
  *(s16x8*)(base + 8000)  = h0v;  *(s16x8*)(base + 8008)      = h1v;
  *(s16x8*)(base + 16000) = l0v;  *(s16x8*)(base + 16008)     = l1v;
}

// ---- Q v5: wave-per-row, fully-coalesced streaming. Lane l loads the row's
// f32x4 at byte offset l*16 (wave = 1KB contiguous, m13 shape). Lane owns
// k in {4l..4l+3}; its c-table slice (16 x f32x4) lives in REGISTERS, loaded
// once. 6-stage shfl_xor reduce; lanes 0-5 store [hi|lo|hi]. No LDS/barriers.
__global__ __launch_bounds__(256) void k_q(
    const float* __restrict__ W, const float* __restrict__ ctf,
    unsigned short* __restrict__ Qs) {
  const int lane = threadIdx.x & 63;
  const int wid = blockIdx.x * 4 + (threadIdx.x >> 6);   // 3908 waves

  // per-lane c-table slice: tab[j][c] = ctf[(4*lane+j)][4c..4c+3], 64 VGPR
  f32x4 tab[4][4];
#pragma unroll
  for (int j = 0; j < 4; ++j)
#pragma unroll
    for (int c = 0; c < 4; ++c)
      tab[j][c] = *(const f32x4*)(ctf + (4 * lane + j) * 16 + 4 * c);

  for (int row = wid; row < 250000; row += 3908) {
    f32x4 wv = *(const f32x4*)(W + (size_t)row * 256 + lane * 4);
    f32x4 a0 = {0.f, 0.f, 0.f, 0.f}, a1 = a0, a2 = a0, a3 = a0;
#pragma unroll
    for (int j = 0; j < 4; ++j) {
      float wsc = wv[j];
      a0 += wsc * tab[j][0];
      a1 += wsc * tab[j][1];
      a2 += wsc * tab[j][2];
      a3 += wsc * tab[j][3];
    }
    // 6-stage butterfly: full 64-lane sum of the 16 accumulators
#pragma unroll
    for (int mask = 1; mask < 64; mask <<= 1) {
#pragma unroll
      for (int e = 0; e < 4; ++e) {
        a0[e] += __shfl_xor(a0[e], mask);
        a1[e] += __shfl_xor(a1[e], mask);
        a2[e] += __shfl_xor(a2[e], mask);
        a3[e] += __shfl_xor(a3[e], mask);
      }
    }
    // epilogue: lanes 0-5 write the 6 16B pieces of [hi | lo | hi]
    if (lane < 6) {
      s16x8 hi01, lo01, hi23, lo23;
      split8(a0, a1, &hi01, &lo01);
      split8(a2, a3, &hi23, &lo23);
      int o = row / 500, sdx = row - o * 500;
      const int piece = lane >> 1, half = lane & 1;
      s16x8 hv = half ? hi23 : hi01;
      s16x8 lv = half ? lo23 : lo01;
      s16x8 v = (piece == 1) ? lv : hv;
      int off = (piece == 0 ? 0 : (piece == 1 ? 8000 : 16000)) + half * 8;
      *(s16x8*)(Qs + (size_t)o * KE + sdx * 16 + off) = v;
    }
  }
}

// ---- final GEMM: pfc[ks] += A'(256xKE) . B'(500xKE)^T over ks-chunk of 960 ----
// grid 400 = ks(25) x bm(2) x bo(8); 4 waves, no LDS, no barriers.
__global__ __launch_bounds__(256) void k_fc(
    const unsigned short* __restrict__ Ps, const unsigned short* __restrict__ Qs,
    float* __restrict__ pfc) {
  const int blk = blockIdx.x;
  const int ks = blk % 25, rest = blk / 25;
  const int bm = rest & 1, bo = rest >> 1;
  const int lane = threadIdx.x & 63, nw = threadIdx.x >> 6;
  const int kbase = ks * 960;
  const int ob = bo * 64 + nw * 16 + (lane & 15);
  const int obc = ob > 499 ? 499 : ob;
  const unsigned short* bp = Qs + (size_t)obc * KE + kbase + (lane >> 4) * 8;
  const unsigned short* ap = Ps + (size_t)(bm * 128 + (lane & 15)) * KE + kbase + (lane >> 4) * 8;
  f32x4 acc[8] = {};
#pragma unroll 3
  for (int st = 0; st < 30; ++st) {
    s16x8 bf = *(const s16x8*)(bp + st * 32);
#pragma unroll
    for (int mf = 0; mf < 8; ++mf) {
      s16x8 af = *(const s16x8*)(ap + (size_t)mf * 16 * KE + st * 32);
      acc[mf] = __builtin_amdgcn_mfma_f32_16x16x32_bf16(af, bf, acc[mf], 0, 0, 0);
    }
  }
  const int col = bo * 64 + nw * 16 + (lane & 15);
  if (col < OUT_) {
    float* pp = pfc + (size_t)ks * 128000;
#pragma unroll
    for (int mf = 0; mf < 8; ++mf) {
#pragma unroll
      for (int r = 0; r < 4; ++r) {
        int row = bm * 128 + mf * 16 + (lane >> 4) * 4 + r;
        pp[row * OUT_ + col] = acc[mf][r];
      }
    }
  }
}

// ---- reduce: out[i] = fc_b[i%500] + sum_ks pfc[ks][i] ----
__global__ void k_red2(const float* __restrict__ pfc, const float* __restrict__ fcb,
                       float* __restrict__ out) {
  int i = blockIdx.x * 256 + threadIdx.x;            // 128000 exact
  int o = i % OUT_;
  float s = fcb[o];
#pragma unroll 5
  for (int ks = 0; ks < 25; ++ks) s += pfc[(size_t)ks * 128000 + i];
  out[i] = s;
}

extern "C" void kernel_launch(void* const* d_in, const int* in_sizes, int n_in,
                              void* d_out, int out_size, void* d_ws, size_t ws_size,
                              hipStream_t stream) {
  const float* x      = (const float*)d_in[0];
  const float* conv_w = (const float*)d_in[1];
  const float* conv_b = (const float*)d_in[2];
  const float* w_ih0  = (const float*)d_in[3];
  const float* b_ih0  = (const float*)d_in[4];
  const float* b_hh0  = (const float*)d_in[5];
  const float* w_ih1  = (const float*)d_in[6];
  const float* b_ih1  = (const float*)d_in[7];
  const float* b_hh1  = (const float*)d_in[8];
  const float* fc_w   = (const float*)d_in[9];
  const float* fc_b   = (const float*)d_in[10];
  float* out = (float*)d_out;

  char* ws = (char*)d_ws;
  float* y            = (float*)ws;                        // 512,000 B
  float* h0n          = (float*)(ws + 524288);             // 16,384 B
  float* h1n          = (float*)(ws + 540672);             // 16,384 B
  float* ctf          = (float*)(ws + 557056);             // 16,384 B
  unsigned short* Ps  = (unsigned short*)(ws + 1048576);   // 12,288,000 B
  unsigned short* Qs  = (unsigned short*)(ws + 14680064);  // 24,000,000 B
  float* pfc          = (float*)(ws + 41943040);           // 12,800,000 B

  k_conv<<<500, 256, 0, stream>>>(x, conv_w, conv_b, y);
  k_h0n<<<16, 256, 0, stream>>>(w_ih0, b_ih0, b_hh0, h0n);
  k_h1n<<<16, 256, 0, stream>>>(h0n, w_ih1, b_ih1, b_hh1, h1n);
  k_cheb<<<16, 256, 0, stream>>>(h1n, ctf);
  k_pgen<<<500, 256, 0, stream>>>(y, Ps);
  k_q<<<977, 256, 0, stream>>>(fc_w, ctf, Qs);
  k_fc<<<400, 256, 0, stream>>>(Ps, Qs, pfc);
  k_red2<<<500, 256, 0, stream>>>(pfc, fc_b, out);
}

// Round 16
// 363.069 us; speedup vs baseline: 1.2482x; 1.0831x over previous
//
#include <hip/hip_runtime.h>
#include <hip/hip_bf16.h>
#include <stdint.h>

#define B_   256
#define C_   10
#define S_   500
#define H_   256
#define OUT_ 500
#define M_   (B_ * S_)   // 128000
#define FCK  (S_ * H_)   // 128000
#define ND   16          // Chebyshev nodes (degree 15)
#define KE   24000       // extended K: [hi|hi|lo] x 500*16
#define PI_F 3.14159265358979f

typedef __attribute__((ext_vector_type(8))) short s16x8;   // 8 bf16
typedef __attribute__((ext_vector_type(4))) float f32x4;

__device__ __forceinline__ unsigned short f2bf(float f) {
  union { float f; unsigned u; } v; v.f = f;
  unsigned r = v.u + 0x7fffu + ((v.u >> 16) & 1u);   // RNE
  return (unsigned short)(r >> 16);
}
__device__ __forceinline__ float bf2f(unsigned short u) {
  union { unsigned u; float f; } v; v.u = ((unsigned)u) << 16; return v.f;
}
__device__ __forceinline__ float sigf(float x) { return 1.0f / (1.0f + __expf(-x)); }
__device__ __forceinline__ float tanh_f(float x) { return 1.0f - 2.0f / (__expf(2.0f * x) + 1.0f); }

// pack 8 f32 -> 8 bf16 via v_cvt_pk_bf16_f32 (S0 low 16, S1 high 16; RNE)
__device__ __forceinline__ s16x8 pack_bf16x8(f32x4 a, f32x4 b) {
  union { s16x8 v; unsigned u[4]; } r;
  asm("v_cvt_pk_bf16_f32 %0, %1, %2" : "=v"(r.u[0]) : "v"(a[0]), "v"(a[1]));
  asm("v_cvt_pk_bf16_f32 %0, %1, %2" : "=v"(r.u[1]) : "v"(a[2]), "v"(a[3]));
  asm("v_cvt_pk_bf16_f32 %0, %1, %2" : "=v"(r.u[2]) : "v"(b[0]), "v"(b[1]));
  asm("v_cvt_pk_bf16_f32 %0, %1, %2" : "=v"(r.u[3]) : "v"(b[2]), "v"(b[3]));
  return r.v;
}

// split 8 f32 into bf16 hi + bf16 lo (lo = x - f32(hi))
__device__ __forceinline__ void split8(f32x4 a, f32x4 b, s16x8* hi, s16x8* lo) {
  union { s16x8 v; unsigned u[4]; } h;
  h.v = pack_bf16x8(a, b);
  union { unsigned u; float f; } c;
  f32x4 ra, rb;
  c.u = h.u[0] << 16;          ra[0] = c.f;
  c.u = h.u[0] & 0xffff0000u;  ra[1] = c.f;
  c.u = h.u[1] << 16;          ra[2] = c.f;
  c.u = h.u[1] & 0xffff0000u;  ra[3] = c.f;
  c.u = h.u[2] << 16;          rb[0] = c.f;
  c.u = h.u[2] & 0xffff0000u;  rb[1] = c.f;
  c.u = h.u[3] << 16;          rb[2] = c.f;
  c.u = h.u[3] & 0xffff0000u;  rb[3] = c.f;
  *hi = h.v;
  *lo = pack_bf16x8(a - ra, b - rb);
}

// ---- conv center tap + relu: y[b*S+s] ----
__global__ void k_conv(const float* __restrict__ x, const float* __restrict__ cw,
                       const float* __restrict__ cb, float* __restrict__ y) {
  int n = blockIdx.x * 256 + threadIdx.x;            // 128000 exact
  int b = n / S_, s = n - b * S_;
  const float* xp = x + (size_t)b * C_ * S_ + s;
  float acc = cb[0];
#pragma unroll
  for (int c = 0; c < C_; ++c) acc += xp[c * S_] * cw[c * 5 + 2];
  y[n] = fmaxf(acc, 0.0f);
}

// ---- h0 at the 16 Chebyshev nodes (pure f32) ----
__global__ void k_h0n(const float* __restrict__ w0, const float* __restrict__ bi0,
                      const float* __restrict__ bh0, float* __restrict__ h0n) {
  int tid = blockIdx.x * 256 + threadIdx.x;          // 4096
  int j = tid >> 8, k = tid & 255;
  float th = PI_F * ((float)j + 0.5f) / 16.0f;
  float yv = (cosf(th) + 1.0f) * 0.5f;               // node in [0,1]
  float gi = yv * w0[k] + bi0[k] + bh0[k];
  float gg = yv * w0[512 + k] + bi0[512 + k] + bh0[512 + k];
  float go = yv * w0[768 + k] + bi0[768 + k] + bh0[768 + k];
  float c = sigf(gi) * tanh_f(gg);
  h0n[tid] = sigf(go) * tanh_f(c);
}

// ---- h1 at the nodes (f32 dots against original f32 w_ih1) ----
__global__ void k_h1n(const float* __restrict__ h0n, const float* __restrict__ w1,
                      const float* __restrict__ b1i, const float* __restrict__ b1h,
                      float* __restrict__ h1n) {
  int tid = blockIdx.x * 256 + threadIdx.x;          // 4096
  int j = tid >> 8, col = tid & 255;
  const float* h  = h0n + j * 256;
  const float* wi = w1 + (size_t)col * 256;
  const float* wg = w1 + (size_t)(512 + col) * 256;
  const float* wo = w1 + (size_t)(768 + col) * 256;
  float gi = b1i[col] + b1h[col];
  float gg = b1i[512 + col] + b1h[512 + col];
  float go = b1i[768 + col] + b1h[768 + col];
  for (int k = 0; k < 256; ++k) {
    float hv = h[k];
    gi += hv * wi[k]; gg += hv * wg[k]; go += hv * wo[k];
  }
  float c = sigf(gi) * tanh_f(gg);
  h1n[tid] = sigf(go) * tanh_f(c);
}

// ---- Chebyshev coefficients via DCT-II -> ctf[k][16] f32 (k-major) ----
__global__ void k_cheb(const float* __restrict__ h1n, float* __restrict__ ctf) {
  int tid = blockIdx.x * 256 + threadIdx.x;          // 4096
  int d = tid >> 8, k = tid & 255;
  float s = 0.f;
  for (int j = 0; j < 16; ++j)
    s += h1n[j * 256 + k] * cosf(PI_F * (float)d * ((float)j + 0.5f) / 16.0f);
  ctf[k * 16 + d] = s * ((d == 0) ? (1.0f / 16.0f) : (2.0f / 16.0f));
}

// ---- P-gen: A'[b][s*16+d] = [T_hi | T_hi | T_lo], T_d = Cheb(2*min(y,1)-1) ----
__global__ void k_pgen(const float* __restrict__ y, unsigned short* __restrict__ Ps) {
  int n = blockIdx.x * 256 + threadIdx.x;            // 128000 exact
  float xv = 2.0f * fminf(y[n], 1.0f) - 1.0f;
  float T[16];
  T[0] = 1.0f; T[1] = xv;
#pragma unroll
  for (int d = 2; d < 16; ++d) T[d] = 2.0f * xv * T[d - 1] - T[d - 2];
  f32x4 t0 = {T[0], T[1], T[2], T[3]},   t1 = {T[4], T[5], T[6], T[7]};
  f32x4 t2 = {T[8], T[9], T[10], T[11]}, t3 = {T[12], T[13], T[14], T[15]};
  s16x8 h0v, l0v, h1v, l1v;
  split8(t0, t1, &h0v, &l0v);
  split8(t2, t3, &h1v, &l1v);
  int bb = n / S_, ss = n - bb * S_;
  unsigned short* base = Ps + (size_t)bb * KE + ss * 16;
  *(s16x8*)(base)         = h0v;  *(s16x8*)(base + 8)         = h1v;
  *(s16x8*)(base + 8000)  = h0v;  *(s16x8*)(base + 8008)      = h1v;
  *(s16x8*)(base + 16000) = l0v;  *(s16x8*)(base + 16008)     = l1v;
}

// ---- Q v6: output-stationary, zero cross-lane. Wave = 16 rows x 16 d.
// lane = (rsub = lane&15 -> row, dg = lane>>4 -> d-quad). Each lane owns the
// full k-sum for (row, 4 d's): acc f32x4. w-loads: 16 rows x 4-way bcast,
// 128B lines reused by 8 consecutive chunks (L1). c-loads: L1-resident 16KB.
// No LDS, no barriers, no shfl. Stores [hi|lo|hi] as 3 x 8B.
__global__ __launch_bounds__(256) void k_q(
    const float* __restrict__ W, const float* __restrict__ ctf,
    unsigned short* __restrict__ Qs) {
  const int lane = threadIdx.x & 63;
  const int wid = blockIdx.x * 4 + (threadIdx.x >> 6);   // 4096 waves
  const int rsub = lane & 15, dg = lane >> 4;
  const float* cp = ctf + dg * 4;

  for (int wg = wid; wg < 15625; wg += 4096) {           // 15625*16 = 250000 rows
    const int row = wg * 16 + rsub;
    const float* wp = W + (size_t)row * 256;
    f32x4 acc = {0.f, 0.f, 0.f, 0.f};
#pragma unroll 4
    for (int kc = 0; kc < 64; ++kc) {
      f32x4 wv = *(const f32x4*)(wp + kc * 4);
      f32x4 c0 = *(const f32x4*)(cp + (kc * 4 + 0) * 16);
      f32x4 c1 = *(const f32x4*)(cp + (kc * 4 + 1) * 16);
      f32x4 c2 = *(const f32x4*)(cp + (kc * 4 + 2) * 16);
      f32x4 c3 = *(const f32x4*)(cp + (kc * 4 + 3) * 16);
      acc += wv[0] * c0 + wv[1] * c1 + wv[2] * c2 + wv[3] * c3;
    }
    // lane holds Q[row][dg*4 .. dg*4+3]; split to bf16 hi/lo, store [hi|lo|hi]
    int o = row / 500, s = row - o * 500;
    union { ushort4 v; unsigned u[2]; } hi, lo;
    asm("v_cvt_pk_bf16_f32 %0, %1, %2" : "=v"(hi.u[0]) : "v"(acc[0]), "v"(acc[1]));
    asm("v_cvt_pk_bf16_f32 %0, %1, %2" : "=v"(hi.u[1]) : "v"(acc[2]), "v"(acc[3]));
    union { unsigned u; float f; } cv;
    f32x4 r;
    cv.u = hi.u[0] << 16;          r[0] = acc[0] - cv.f;
    cv.u = hi.u[0] & 0xffff0000u;  r[1] = acc[1] - cv.f;
    cv.u = hi.u[1] << 16;          r[2] = acc[2] - cv.f;
    cv.u = hi.u[1] & 0xffff0000u;  r[3] = acc[3] - cv.f;
    asm("v_cvt_pk_bf16_f32 %0, %1, %2" : "=v"(lo.u[0]) : "v"(r[0]), "v"(r[1]));
    asm("v_cvt_pk_bf16_f32 %0, %1, %2" : "=v"(lo.u[1]) : "v"(r[2]), "v"(r[3]));
    unsigned short* qb = Qs + (size_t)o * KE + s * 16 + dg * 4;
    *(ushort4*)(qb)         = hi.v;
    *(ushort4*)(qb + 8000)  = lo.v;
    *(ushort4*)(qb + 16000) = hi.v;
  }
}

// ---- final GEMM: pfc[ks] += A'(256xKE) . B'(500xKE)^T over ks-chunk of 960 ----
// grid 400 = ks(25) x bm(2) x bo(8); 4 waves, no LDS, no barriers.
__global__ __launch_bounds__(256) void k_fc(
    const unsigned short* __restrict__ Ps, const unsigned short* __restrict__ Qs,
    float* __restrict__ pfc) {
  const int blk = blockIdx.x;
  const int ks = blk % 25, rest = blk / 25;
  const int bm = rest & 1, bo = rest >> 1;
  const int lane = threadIdx.x & 63, nw = threadIdx.x >> 6;
  const int kbase = ks * 960;
  const int ob = bo * 64 + nw * 16 + (lane & 15);
  const int obc = ob > 499 ? 499 : ob;
  const unsigned short* bp = Qs + (size_t)obc * KE + kbase + (lane >> 4) * 8;
  const unsigned short* ap = Ps + (size_t)(bm * 128 + (lane & 15)) * KE + kbase + (lane >> 4) * 8;
  f32x4 acc[8] = {};
#pragma unroll 3
  for (int st = 0; st < 30; ++st) {
    s16x8 bf = *(const s16x8*)(bp + st * 32);
#pragma unroll
    for (int mf = 0; mf < 8; ++mf) {
      s16x8 af = *(const s16x8*)(ap + (size_t)mf * 16 * KE + st * 32);
      acc[mf] = __builtin_amdgcn_mfma_f32_16x16x32_bf16(af, bf, acc[mf], 0, 0, 0);
    }
  }
  const int col = bo * 64 + nw * 16 + (lane & 15);
  if (col < OUT_) {
    float* pp = pfc + (size_t)ks * 128000;
#pragma unroll
    for (int mf = 0; mf < 8; ++mf) {
#pragma unroll
      for (int r = 0; r < 4; ++r) {
        int row = bm * 128 + mf * 16 + (lane >> 4) * 4 + r;
        pp[row * OUT_ + col] = acc[mf][r];
      }
    }
  }
}

// ---- reduce: out[i] = fc_b[i%500] + sum_ks pfc[ks][i] ----
__global__ void k_red2(const float* __restrict__ pfc, const float* __restrict__ fcb,
                       float* __restrict__ out) {
  int i = blockIdx.x * 256 + threadIdx.x;            // 128000 exact
  int o = i % OUT_;
  float s = fcb[o];
#pragma unroll 5
  for (int ks = 0; ks < 25; ++ks) s += pfc[(size_t)ks * 128000 + i];
  out[i] = s;
}

extern "C" void kernel_launch(void* const* d_in, const int* in_sizes, int n_in,
                              void* d_out, int out_size, void* d_ws, size_t ws_size,
                              hipStream_t stream) {
  const float* x      = (const float*)d_in[0];
  const float* conv_w = (const float*)d_in[1];
  const float* conv_b = (const float*)d_in[2];
  const float* w_ih0  = (const float*)d_in[3];
  const float* b_ih0  = (const float*)d_in[4];
  const float* b_hh0  = (const float*)d_in[5];
  const float* w_ih1  = (const float*)d_in[6];
  const float* b_ih1  = (const float*)d_in[7];
  const float* b_hh1  = (const float*)d_in[8];
  const float* fc_w   = (const float*)d_in[9];
  const float* fc_b   = (const float*)d_in[10];
  float* out = (float*)d_out;

  char* ws = (char*)d_ws;
  float* y            = (float*)ws;                        // 512,000 B
  float* h0n          = (float*)(ws + 524288);             // 16,384 B
  float* h1n          = (float*)(ws + 540672);             // 16,384 B
  float* ctf          = (float*)(ws + 557056);             // 16,384 B
  unsigned short* Ps  = (unsigned short*)(ws + 1048576);   // 12,288,000 B
  unsigned short* Qs  = (unsigned short*)(ws + 14680064);  // 24,000,000 B
  float* pfc          = (float*)(ws + 41943040);           // 12,800,000 B

  k_conv<<<500, 256, 0, stream>>>(x, conv_w, conv_b, y);
  k_h0n<<<16, 256, 0, stream>>>(w_ih0, b_ih0, b_hh0, h0n);
  k_h1n<<<16, 256, 0, stream>>>(h0n, w_ih1, b_ih1, b_hh1, h1n);
  k_cheb<<<16, 256, 0, stream>>>(h1n, ctf);
  k_pgen<<<500, 256, 0, stream>>>(y, Ps);
  k_q<<<1024, 256, 0, stream>>>(fc_w, ctf, Qs);
  k_fc<<<400, 256, 0, stream>>>(Ps, Qs, pfc);
  k_red2<<<500, 256, 0, stream>>>(pfc, fc_b, out);
}

// Round 18
// 203.688 us; speedup vs baseline: 2.2249x; 1.7825x over previous
//
#include <hip/hip_runtime.h>
#include <hip/hip_bf16.h>
#include <stdint.h>

#define B_   256
#define C_   10
#define S_   500
#define H_   256
#define OUT_ 500
#define M_   (B_ * S_)   // 128000
#define FCK  (S_ * H_)   // 128000
#define ND   16          // Chebyshev nodes (degree 15)
#define KE   24000       // extended K: [hi|hi|lo] x 500*16
#define PI_F 3.14159265358979f

typedef __attribute__((ext_vector_type(8))) short s16x8;   // 8 bf16
typedef __attribute__((ext_vector_type(4))) float f32x4;

__device__ __forceinline__ unsigned short f2bf(float f) {
  union { float f; unsigned u; } v; v.f = f;
  unsigned r = v.u + 0x7fffu + ((v.u >> 16) & 1u);   // RNE
  return (unsigned short)(r >> 16);
}
__device__ __forceinline__ float bf2f(unsigned short u) {
  union { unsigned u; float f; } v; v.u = ((unsigned)u) << 16; return v.f;
}
__device__ __forceinline__ float sigf(float x) { return 1.0f / (1.0f + __expf(-x)); }
__device__ __forceinline__ float tanh_f(float x) { return 1.0f - 2.0f / (__expf(2.0f * x) + 1.0f); }

// pack 8 f32 -> 8 bf16 via v_cvt_pk_bf16_f32 (S0 low 16, S1 high 16; RNE)
__device__ __forceinline__ s16x8 pack_bf16x8(f32x4 a, f32x4 b) {
  union { s16x8 v; unsigned u[4]; } r;
  asm("v_cvt_pk_bf16_f32 %0, %1, %2" : "=v"(r.u[0]) : "v"(a[0]), "v"(a[1]));
  asm("v_cvt_pk_bf16_f32 %0, %1, %2" : "=v"(r.u[1]) : "v"(a[2]), "v"(a[3]));
  asm("v_cvt_pk_bf16_f32 %0, %1, %2" : "=v"(r.u[2]) : "v"(b[0]), "v"(b[1]));
  asm("v_cvt_pk_bf16_f32 %0, %1, %2" : "=v"(r.u[3]) : "v"(b[2]), "v"(b[3]));
  return r.v;
}

// split 8 f32 into bf16 hi + bf16 lo (lo = x - f32(hi))
__device__ __forceinline__ void split8(f32x4 a, f32x4 b, s16x8* hi, s16x8* lo) {
  union { s16x8 v; unsigned u[4]; } h;
  h.v = pack_bf16x8(a, b);
  union { unsigned u; float f; } c;
  f32x4 ra, rb;
  c.u = h.u[0] << 16;          ra[0] = c.f;
  c.u = h.u[0] & 0xffff0000u;  ra[1] = c.f;
  c.u = h.u[1] << 16;          ra[2] = c.f;
  c.u = h.u[1] & 0xffff0000u;  ra[3] = c.f;
  c.u = h.u[2] << 16;          rb[0] = c.f;
  c.u = h.u[2] & 0xffff0000u;  rb[1] = c.f;
  c.u = h.u[3] << 16;          rb[2] = c.f;
  c.u = h.u[3] & 0xffff0000u;  rb[3] = c.f;
  *hi = h.v;
  *lo = pack_bf16x8(a - ra, b - rb);
}

// ---- conv center tap + relu: y[b*S+s] ----
__global__ void k_conv(const float* __restrict__ x, const float* __restrict__ cw,
                       const float* __restrict__ cb, float* __restrict__ y) {
  int n = blockIdx.x * 256 + threadIdx.x;            // 128000 exact
  int b = n / S_, s = n - b * S_;
  const float* xp = x + (size_t)b * C_ * S_ + s;
  float acc = cb[0];
#pragma unroll
  for (int c = 0; c < C_; ++c) acc += xp[c * S_] * cw[c * 5 + 2];
  y[n] = fmaxf(acc, 0.0f);
}

// ---- h0 at the 16 Chebyshev nodes (pure f32) ----
__global__ void k_h0n(const float* __restrict__ w0, const float* __restrict__ bi0,
                      const float* __restrict__ bh0, float* __restrict__ h0n) {
  int tid = blockIdx.x * 256 + threadIdx.x;          // 4096
  int j = tid >> 8, k = tid & 255;
  float th = PI_F * ((float)j + 0.5f) / 16.0f;
  float yv = (cosf(th) + 1.0f) * 0.5f;               // node in [0,1]
  float gi = yv * w0[k] + bi0[k] + bh0[k];
  float gg = yv * w0[512 + k] + bi0[512 + k] + bh0[512 + k];
  float go = yv * w0[768 + k] + bi0[768 + k] + bh0[768 + k];
  float c = sigf(gi) * tanh_f(gg);
  h0n[tid] = sigf(go) * tanh_f(c);
}

// ---- h1 at the nodes (f32 dots against original f32 w_ih1) ----
__global__ void k_h1n(const float* __restrict__ h0n, const float* __restrict__ w1,
                      const float* __restrict__ b1i, const float* __restrict__ b1h,
                      float* __restrict__ h1n) {
  int tid = blockIdx.x * 256 + threadIdx.x;          // 4096
  int j = tid >> 8, col = tid & 255;
  const float* h  = h0n + j * 256;
  const float* wi = w1 + (size_t)col * 256;
  const float* wg = w1 + (size_t)(512 + col) * 256;
  const float* wo = w1 + (size_t)(768 + col) * 256;
  float gi = b1i[col] + b1h[col];
  float gg = b1i[512 + col] + b1h[512 + col];
  float go = b1i[768 + col] + b1h[768 + col];
  for (int k = 0; k < 256; ++k) {
    float hv = h[k];
    gi += hv * wi[k]; gg += hv * wg[k]; go += hv * wo[k];
  }
  float c = sigf(gi) * tanh_f(gg);
  h1n[tid] = sigf(go) * tanh_f(c);
}

// ---- Chebyshev coefficients via DCT-II -> ctf[k][16] f32 (k-major) ----
__global__ void k_cheb(const float* __restrict__ h1n, float* __restrict__ ctf) {
  int tid = blockIdx.x * 256 + threadIdx.x;          // 4096
  int d = tid >> 8, k = tid & 255;
  float s = 0.f;
  for (int j = 0; j < 16; ++j)
    s += h1n[j * 256 + k] * cosf(PI_F * (float)d * ((float)j + 0.5f) / 16.0f);
  ctf[k * 16 + d] = s * ((d == 0) ? (1.0f / 16.0f) : (2.0f / 16.0f));
}

// ---- P-gen: A'[b][s*16+d] = [T_hi | T_hi | T_lo], T_d = Cheb(2*min(y,1)-1) ----
__global__ void k_pgen(const float* __restrict__ y, unsigned short* __restrict__ Ps) {
  int n = blockIdx.x * 256 + threadIdx.x;            // 128000 exact
  float xv = 2.0f * fminf(y[n], 1.0f) - 1.0f;
  float T[16];
  T[0] = 1.0f; T[1] = xv;
#pragma unroll
  for (int d = 2; d < 16; ++d) T[d] = 2.0f * xv * T[d - 1] - T[d - 2];
  f32x4 t0 = {T[0], T[1], T[2], T[3]},   t1 = {T[4], T[5], T[6], T[7]};
  f32x4 t2 = {T[8], T[9], T[10], T[11]}, t3 = {T[12], T[13], T[14], T[15]};
  s16x8 h0v, l0v, h1v, l1v;
  split8(t0, t1, &h0v, &l0v);
  split8(t2, t3, &h1v, &l1v);
  int bb = n / S_, ss = n - bb * S_;
  unsigned short* base = Ps + (size_t)bb * KE + ss * 16;
  *(s16x8*)(base)         = h0v;  *(s16x8*)(base + 8)         = h1v;
  *(s16x8*)(base + 8000)  = h0v;  *(s16x8*)(base + 8008)      = h1v;
  *(s16x8*)(base + 16000) = l0v;  *(s16x8*)(base + 16008)     = l1v;
}

// ---- Q v8: wave-per-row (lane owns k=4l..4l+3, c-table slice in 64 VGPR,
// coalesced 1KB wave-load) + HALVING reduce: 17 shfl/row (vs v5's 96).
// Lane g=lane&15 ends owning d = bitrev4(g); stages 5,6 complete 64-lane sum.
// Next-row load double-buffered under the reduce. No LDS, no barriers.
__global__ __launch_bounds__(256) void k_q(
    const float* __restrict__ W, const float* __restrict__ ctf,
    unsigned short* __restrict__ Qs) {
  const int lane = threadIdx.x & 63;
  const int wid = blockIdx.x * 4 + (threadIdx.x >> 6);   // 3908 waves

  // per-lane c-table slice: tab[j][c] = ctf[(4*lane+j)][4c..4c+3]  (64 VGPR)
  f32x4 tab[4][4];
#pragma unroll
  for (int j = 0; j < 4; ++j)
#pragma unroll
    for (int c = 0; c < 4; ++c)
      tab[j][c] = *(const f32x4*)(ctf + (4 * lane + j) * 16 + 4 * c);

  const int g = lane & 15;
  const int d = ((g & 1) << 3) | ((g & 2) << 1) | ((g & 4) >> 1) | ((g & 8) >> 3);

  int row = wid;
  f32x4 wv = {0.f, 0.f, 0.f, 0.f};
  if (row < 250000) wv = *(const f32x4*)(W + (size_t)row * 256 + lane * 4);

  while (row < 250000) {
    const int nrow = row + 3908;
    f32x4 wn = wv;
    if (nrow < 250000) wn = *(const f32x4*)(W + (size_t)nrow * 256 + lane * 4);

    f32x4 a0 = {0.f, 0.f, 0.f, 0.f}, a1 = a0, a2 = a0, a3 = a0;
#pragma unroll
    for (int j = 0; j < 4; ++j) {
      float wsc = wv[j];
      a0 += wsc * tab[j][0];
      a1 += wsc * tab[j][1];
      a2 += wsc * tab[j][2];
      a3 += wsc * tab[j][3];
    }

    // stage 1 (mask 1): 16 -> 8 values
    const bool kl1 = (lane & 1) == 0;
    f32x4 k0 = kl1 ? a0 : a2, k1 = kl1 ? a1 : a3;
    f32x4 s0 = kl1 ? a2 : a0, s1 = kl1 ? a3 : a1;
#pragma unroll
    for (int e = 0; e < 4; ++e) {
      s0[e] = __shfl_xor(s0[e], 1);
      s1[e] = __shfl_xor(s1[e], 1);
    }
    f32x4 b0 = k0 + s0, b1 = k1 + s1;
    // stage 2 (mask 2): 8 -> 4
    const bool kl2 = (lane & 2) == 0;
    f32x4 k2 = kl2 ? b0 : b1, s2 = kl2 ? b1 : b0;
#pragma unroll
    for (int e = 0; e < 4; ++e) s2[e] = __shfl_xor(s2[e], 2);
    f32x4 c4 = k2 + s2;
    // stage 3 (mask 4): 4 -> 2
    const bool kl3 = (lane & 4) == 0;
    float p0 = kl3 ? c4[0] : c4[2], p1 = kl3 ? c4[1] : c4[3];
    float q0 = kl3 ? c4[2] : c4[0], q1 = kl3 ? c4[3] : c4[1];
    q0 = __shfl_xor(q0, 4); q1 = __shfl_xor(q1, 4);
    float e0 = p0 + q0, e1 = p1 + q1;
    // stage 4 (mask 8): 2 -> 1
    const bool kl4 = (lane & 8) == 0;
    float kv = kl4 ? e0 : e1, sv = kl4 ? e1 : e0;
    float v = kv + __shfl_xor(sv, 8);
    // stages 5,6: sum the 4 16-lane groups
    v += __shfl_xor(v, 16);
    v += __shfl_xor(v, 32);

    // epilogue: lanes 0-15 store hi/lo/hi (2B each) for their d
    if (lane < 16) {
      int o = row / 500, sdx = row - o * 500;
      unsigned short hi = f2bf(v);
      unsigned short lo = f2bf(v - bf2f(hi));
      unsigned short* qb = Qs + (size_t)o * KE + sdx * 16;
      qb[d] = hi;
      qb[8000 + d] = lo;
      qb[16000 + d] = hi;
    }
    wv = wn;
    row = nrow;
  }
}

// ---- final GEMM: pfc[ks] += A'(256xKE) . B'(500xKE)^T over ks-chunk of 960 ----
// grid 400 = ks(25) x bm(2) x bo(8); 4 waves, no LDS, no barriers.
__global__ __launch_bounds__(256) void k_fc(
    const unsigned short* __restrict__ Ps, const unsigned short* __restrict__ Qs,
    float* __restrict__ pfc) {
  const int blk = blockIdx.x;
  const int ks = blk % 25, rest = blk / 25;
  const int bm = rest & 1, bo = rest >> 1;
  const int lane = threadIdx.x & 63, nw = threadIdx.x >> 6;
  const int kbase = ks * 960;
  const int ob = bo * 64 + nw * 16 + (lane & 15);
  const int obc = ob > 499 ? 499 : ob;
  const unsigned short* bp = Qs + (size_t)obc * KE + kbase + (lane >> 4) * 8;
  const unsigned short* ap = Ps + (size_t)(bm * 128 + (lane & 15)) * KE + kbase + (lane >> 4) * 8;
  f32x4 acc[8] = {};
#pragma unroll 3
  for (int st = 0; st < 30; ++st) {
    s16x8 bf = *(const s16x8*)(bp + st * 32);
#pragma unroll
    for (int mf = 0; mf < 8; ++mf) {
      s16x8 af = *(const s16x8*)(ap + (size_t)mf * 16 * KE + st * 32);
      acc[mf] = __builtin_amdgcn_mfma_f32_16x16x32_bf16(af, bf, acc[mf], 0, 0, 0);
    }
  }
  const int col = bo * 64 + nw * 16 + (lane & 15);
  if (col < OUT_) {
    float* pp = pfc + (size_t)ks * 128000;
#pragma unroll
    for (int mf = 0; mf < 8; ++mf) {
#pragma unroll
      for (int r = 0; r < 4; ++r) {
        int row = bm * 128 + mf * 16 + (lane >> 4) * 4 + r;
        pp[row * OUT_ + col] = acc[mf][r];
      }
    }
  }
}

// ---- reduce: out[i] = fc_b[i%500] + sum_ks pfc[ks][i] ----
__global__ void k_red2(const float* __restrict__ pfc, const float* __restrict__ fcb,
                       float* __restrict__ out) {
  int i = blockIdx.x * 256 + threadIdx.x;            // 128000 exact
  int o = i % OUT_;
  float s = fcb[o];
#pragma unroll 5
  for (int ks = 0; ks < 25; ++ks) s += pfc[(size_t)ks * 128000 + i];
  out[i] = s;
}

extern "C" void kernel_launch(void* const* d_in, const int* in_sizes, int n_in,
                              void* d_out, int out_size, void* d_ws, size_t ws_size,
                              hipStream_t stream) {
  const float* x      = (const float*)d_in[0];
  const float* conv_w = (const float*)d_in[1];
  const float* conv_b = (const float*)d_in[2];
  const float* w_ih0  = (const float*)d_in[3];
  const float* b_ih0  = (const float*)d_in[4];
  const float* b_hh0  = (const float*)d_in[5];
  const float* w_ih1  = (const float*)d_in[6];
  const float* b_ih1  = (const float*)d_in[7];
  const float* b_hh1  = (const float*)d_in[8];
  const float* fc_w   = (const float*)d_in[9];
  const float* fc_b   = (const float*)d_in[10];
  float* out = (float*)d_out;

  char* ws = (char*)d_ws;
  float* y            = (float*)ws;                        // 512,000 B
  float* h0n          = (float*)(ws + 524288);             // 16,384 B
  float* h1n          = (float*)(ws + 540672);             // 16,384 B
  float* ctf          = (float*)(ws + 557056);             // 16,384 B
  unsigned short* Ps  = (unsigned short*)(ws + 1048576);   // 12,288,000 B
  unsigned short* Qs  = (unsigned short*)(ws + 14680064);  // 24,000,000 B
  float* pfc          = (float*)(ws + 41943040);           // 12,800,000 B

  k_conv<<<500, 256, 0, stream>>>(x, conv_w, conv_b, y);
  k_h0n<<<16, 256, 0, stream>>>(w_ih0, b_ih0, b_hh0, h0n);
  k_h1n<<<16, 256, 0, stream>>>(h0n, w_ih1, b_ih1, b_hh1, h1n);
  k_cheb<<<16, 256, 0, stream>>>(h1n, ctf);
  k_pgen<<<500, 256, 0, stream>>>(y, Ps);
  k_q<<<977, 256, 0, stream>>>(fc_w, ctf, Qs);
  k_fc<<<400, 256, 0, stream>>>(Ps, Qs, pfc);
  k_red2<<<500, 256, 0, stream>>>(pfc, fc_b, out);
}